// Round 8
// baseline (155.801 us; speedup 1.0000x reference)
//
#include <hip/hip_runtime.h>
#include <hip/hip_bf16.h>

#define NVOX 131072
#define KOFF 27
#define PPAIR 32768
#define CIN 64
#define COUT 64
#define PPB 128          // pairs per conv block
#define FS 72            // padded bf16 stride (144 B)
#define TOTP (KOFF * PPAIR)
#define CAP 12           // slots per output row (fixed-capacity path)
#define OVF_MAX 8192

typedef __attribute__((ext_vector_type(8))) short bf16x8;
typedef __attribute__((ext_vector_type(4))) float f32x4;
typedef __attribute__((ext_vector_type(4))) unsigned int u32x4;
typedef __attribute__((ext_vector_type(2))) unsigned int u32x2;

static constexpr size_t WIMG_BYTES = (size_t)KOFF * COUT * FS * 2;      // 248832
static constexpr size_t FB_BYTES   = ((size_t)NVOX + 1) * CIN * 2;      // 16.78 MB

// ---- fixed-capacity (primary) workspace layout ----
static constexpr size_t YC_OFF    = 0;
static constexpr size_t YC_BYTES  = (size_t)NVOX * CAP * COUT * 2;      // 201.3 MB
static constexpr size_t CUR2_OFF  = YC_OFF + YC_BYTES;
static constexpr size_t OVFC_OFF  = CUR2_OFF + (size_t)NVOX * 4;
static constexpr size_t OVF_OFF   = OVFC_OFF + 256;
static constexpr size_t WIMG2_OFF = OVF_OFF + (size_t)OVF_MAX * 4;
static constexpr size_t FB2_OFF   = (WIMG2_OFF + WIMG_BYTES + 255) & ~(size_t)255;
static constexpr size_t WS_CAP    = FB2_OFF + FB_BYTES;                 // ~219 MB

// ---- counting-sort (mid-tier) workspace layout ----
static constexpr size_t Y_OFF     = 0;
static constexpr size_t Y_BYTES   = (size_t)TOTP * COUT * 2;            // 113.25 MB
static constexpr size_t RANK_OFF  = Y_OFF + Y_BYTES;
static constexpr size_t CNT_OFF   = RANK_OFF + (size_t)TOTP * 4;
static constexpr size_t START_OFF = CNT_OFF + (size_t)NVOX * 4;
static constexpr size_t BSUM_OFF  = START_OFF + ((size_t)NVOX + 64) * 4;
static constexpr size_t BOFF_OFF  = BSUM_OFF + 512 * 4;
static constexpr size_t WIMG_OFF  = BOFF_OFF + 520 * 4;
static constexpr size_t FB_OFF    = (WIMG_OFF + WIMG_BYTES + 255) & ~(size_t)255;
static constexpr size_t WS_FULL   = FB_OFF + FB_BYTES;                  // ~135 MB

__device__ __forceinline__ unsigned short f2bf(float f) {
    union { __hip_bfloat16 h; unsigned short u; } v;
    v.h = __float2bfloat16(f);
    return v.u;
}
__device__ __forceinline__ float bfbits2f(unsigned int u) {
    union { unsigned int i; float f; } v; v.i = u << 16; return v.f;
}

#define NB_F2B 4096                       // NVOX*CIN/8/256
#define NB_WP  KOFF
#define NB_RNK (TOTP / 256)

// ================= prep2 (cap path): feat->bf16 | weight image, NO atomics =================
__global__ __launch_bounds__(256) void prep2_kernel(
    const float* __restrict__ f, unsigned short* __restrict__ fb,
    const float* __restrict__ w, unsigned short* __restrict__ wimg)
{
    const int bid = blockIdx.x;
    const int tid = threadIdx.x;
    if (bid < NB_F2B) {
        int i = bid * 256 + tid;
        float4 a = ((const float4*)f)[i * 2];
        float4 b = ((const float4*)f)[i * 2 + 1];
        union { u32x4 u; unsigned short s[8]; } pk;
        pk.s[0]=f2bf(a.x); pk.s[1]=f2bf(a.y); pk.s[2]=f2bf(a.z); pk.s[3]=f2bf(a.w);
        pk.s[4]=f2bf(b.x); pk.s[5]=f2bf(b.y); pk.s[6]=f2bf(b.z); pk.s[7]=f2bf(b.w);
        ((u32x4*)fb)[i] = pk.u;
    } else {
        const int k    = bid - NB_F2B;
        const int cout = tid & 63;
        const int ci0  = (tid >> 6) * 16;
        const float* wk = w + (size_t)k * CIN * COUT;
        union { u32x4 u[2]; unsigned short s[16]; } pk;
#pragma unroll
        for (int i = 0; i < 16; ++i)
            pk.s[i] = f2bf(wk[(ci0 + i) * COUT + cout]);
        unsigned short* dst = wimg + (size_t)k * COUT * FS + cout * FS + ci0;
        *(u32x4*)dst       = pk.u[0];
        *(u32x4*)(dst + 8) = pk.u[1];
        if (k == 0 && tid < CIN) fb[(size_t)NVOX * CIN + tid] = 0;  // zero row
    }
}

// ================= conv5 (cap path): gather -> MFMA -> bucketed-Y =================
__global__ __launch_bounds__(256) void conv5_kernel(
    const unsigned short* __restrict__ featbf,
    const unsigned short* __restrict__ wimg,     // [k][cout][ci] stride FS
    const int* __restrict__ in_map,
    const int* __restrict__ out_map,
    int* __restrict__ cursor,
    int* __restrict__ ovf_cnt,
    int* __restrict__ ovf,
    unsigned short* __restrict__ Ybf)
{
    __shared__ unsigned short Fl[PPB * FS];     // 18432 B
    __shared__ unsigned short Wt[COUT * FS];    //  9216 B

    const int tid  = threadIdx.x;
    const int wave = tid >> 6;
    const int lane = tid & 63;
    const int k    = blockIdx.x >> 8;
    const int pb   = blockIdx.x & 255;
    const int base = k * PPAIR + pb * PPB;

    // ---- stage Wt (9216 B = 9 chunks of 1 KiB) ----
    {
        const unsigned short* wsrc = wimg + (size_t)k * COUT * FS;
        for (int c = wave; c < 9; c += 4)
            __builtin_amdgcn_global_load_lds(
                (const __attribute__((address_space(1))) void*)(wsrc + c * 512 + lane * 8),
                (__attribute__((address_space(3))) void*)(&Wt[c * 512 + lane * 8]),
                16, 0, 0);
    }

    // ---- branchless gather: 2 threads/row, 64 B each ----
    {
        const int row = tid >> 1;
        const int h   = tid & 1;
        int im = in_map[base + row];
        const u32x4* src = (const u32x4*)(featbf + (size_t)(im >= 0 ? im : NVOX) * CIN + h * 32);
        u32x4 v0 = src[0], v1 = src[1], v2 = src[2], v3 = src[3];
        u32x4* dst = (u32x4*)&Fl[row * FS + h * 32];
        dst[0] = v0; dst[1] = v1; dst[2] = v2; dst[3] = v3;
    }
    __syncthreads();

    // ---- MFMA: wave computes 32 pairs x 64 couts ----
    const int r = lane & 15;
    const int g = lane >> 4;

    bf16x8 af[2][2];
    bf16x8 bfr[4][2];
#pragma unroll
    for (int m = 0; m < 2; ++m)
#pragma unroll
        for (int s = 0; s < 2; ++s)
            af[m][s] = *(const bf16x8*)&Fl[(wave * 32 + m * 16 + r) * FS + s * 32 + g * 8];
#pragma unroll
    for (int n = 0; n < 4; ++n)
#pragma unroll
        for (int s = 0; s < 2; ++s)
            bfr[n][s] = *(const bf16x8*)&Wt[(n * 16 + r) * FS + s * 32 + g * 8];

    f32x4 acc[2][4];
#pragma unroll
    for (int m = 0; m < 2; ++m)
#pragma unroll
        for (int n = 0; n < 4; ++n)
            acc[m][n] = (f32x4){0.f, 0.f, 0.f, 0.f};

#pragma unroll
    for (int s = 0; s < 2; ++s)
#pragma unroll
        for (int m = 0; m < 2; ++m)
#pragma unroll
            for (int n = 0; n < 4; ++n)
                acc[m][n] = __builtin_amdgcn_mfma_f32_16x16x32_bf16(
                    af[m][s], bfr[n][s], acc[m][n], 0, 0, 0);

    // ---- stage C (bf16) into wave-private Fl rows ----
#pragma unroll
    for (int m = 0; m < 2; ++m)
#pragma unroll
        for (int n = 0; n < 4; ++n)
#pragma unroll
            for (int j = 0; j < 4; ++j)
                Fl[(wave * 32 + m * 16 + g * 4 + j) * FS + n * 16 + r] = f2bf(acc[m][n][j]);

    // ---- copy out: slot = o*CAP + cursor++ (overflow -> list) ----
    {
        const int p = tid >> 1;
        const int h = tid & 1;
        int o = out_map[base + p];
        int s = -1;
        if (h == 0 && o >= 0) {
            int r0 = atomicAdd(&cursor[o], 1);
            if (r0 < CAP) {
                s = o * CAP + r0;
            } else {
                int idx = atomicAdd(ovf_cnt, 1);
                if (idx < OVF_MAX) ovf[idx] = base + p;
            }
        }
        s = __shfl(s, lane & 62);
        if (s >= 0) {
            const unsigned short* src = &Fl[p * FS + h * 32];
            u32x4* dst = (u32x4*)(Ybf + (size_t)s * COUT + h * 32);
            u32x4 v0 = *(const u32x4*)(src + 0);
            u32x4 v1 = *(const u32x4*)(src + 8);
            u32x4 v2 = *(const u32x4*)(src + 16);
            u32x4 v3 = *(const u32x4*)(src + 24);
            dst[0] = v0; dst[1] = v1; dst[2] = v2; dst[3] = v3;
        }
    }
}

// ================= gather (cap path) =================
__global__ __launch_bounds__(256) void gather_cap_kernel(
    const unsigned short* __restrict__ Y,
    const int* __restrict__ cursor,
    const float* __restrict__ bias,
    float* __restrict__ out)
{
    const int row  = blockIdx.x * 4 + (threadIdx.x >> 6);
    const int lane = threadIdx.x & 63;
    const int c4   = (lane & 15) * 4;
    const int grp  = lane >> 4;

    int cnt = cursor[row];
    if (cnt > CAP) cnt = CAP;
    const unsigned short* yb = Y + (size_t)row * CAP * COUT;

    float4 acc = {0.f, 0.f, 0.f, 0.f};
    for (int j = grp; j < cnt; j += 4) {
        u32x2 v = *(const u32x2*)&yb[j * COUT + c4];
        acc.x += bfbits2f(v.x & 0xffffu);
        acc.y += bfbits2f(v.x >> 16);
        acc.z += bfbits2f(v.y & 0xffffu);
        acc.w += bfbits2f(v.y >> 16);
    }
    acc.x += __shfl_xor(acc.x, 16); acc.y += __shfl_xor(acc.y, 16);
    acc.z += __shfl_xor(acc.z, 16); acc.w += __shfl_xor(acc.w, 16);
    acc.x += __shfl_xor(acc.x, 32); acc.y += __shfl_xor(acc.y, 32);
    acc.z += __shfl_xor(acc.z, 32); acc.w += __shfl_xor(acc.w, 32);

    if (grp == 0) {
        float4 b = *(const float4*)&bias[c4];
        float4 rv = {acc.x + b.x, acc.y + b.y, acc.z + b.z, acc.w + b.w};
        *(float4*)&out[(size_t)row * COUT + c4] = rv;
    }
}

// ================= overflow fixup (runs after gather) =================
__global__ __launch_bounds__(256) void fixup_kernel(
    const unsigned short* __restrict__ fb,
    const unsigned short* __restrict__ wimg,
    const int* __restrict__ in_map,
    const int* __restrict__ out_map,
    const int* __restrict__ ovf_cnt,
    const int* __restrict__ ovf,
    float* __restrict__ out)
{
    int n = ovf_cnt[0];
    if (n > OVF_MAX) n = OVF_MAX;
    const int lane = threadIdx.x & 63;
    const int wid  = (blockIdx.x * 256 + threadIdx.x) >> 6;
    const int nw   = (gridDim.x * 256) >> 6;
    for (int e = wid; e < n; e += nw) {
        int t  = ovf[e];
        int k  = t >> 15;                 // t / PPAIR
        int in = in_map[t];
        int o  = out_map[t];
        const unsigned short* fr = fb + (size_t)in * CIN;
        const unsigned short* wr = wimg + (size_t)k * COUT * FS + lane * FS;
        float acc = 0.f;
#pragma unroll 8
        for (int ci = 0; ci < CIN; ++ci)
            acc += bfbits2f(fr[ci]) * bfbits2f(wr[ci]);
        unsafeAtomicAdd(out + (size_t)o * COUT + lane, acc);
    }
}

// ================= counting-sort mid-tier (round-7 verified path) =================
__global__ __launch_bounds__(256) void prep_kernel(
    const float* __restrict__ f, unsigned short* __restrict__ fb,
    const float* __restrict__ w, unsigned short* __restrict__ wimg,
    const int* __restrict__ out_map, int* __restrict__ counts,
    int* __restrict__ rank)
{
    const int bid = blockIdx.x;
    const int tid = threadIdx.x;
    if (bid < NB_F2B) {
        int i = bid * 256 + tid;
        float4 a = ((const float4*)f)[i * 2];
        float4 b = ((const float4*)f)[i * 2 + 1];
        union { u32x4 u; unsigned short s[8]; } pk;
        pk.s[0]=f2bf(a.x); pk.s[1]=f2bf(a.y); pk.s[2]=f2bf(a.z); pk.s[3]=f2bf(a.w);
        pk.s[4]=f2bf(b.x); pk.s[5]=f2bf(b.y); pk.s[6]=f2bf(b.z); pk.s[7]=f2bf(b.w);
        ((u32x4*)fb)[i] = pk.u;
    } else if (bid < NB_F2B + NB_WP) {
        const int k    = bid - NB_F2B;
        const int cout = tid & 63;
        const int ci0  = (tid >> 6) * 16;
        const float* wk = w + (size_t)k * CIN * COUT;
        union { u32x4 u[2]; unsigned short s[16]; } pk;
#pragma unroll
        for (int i = 0; i < 16; ++i)
            pk.s[i] = f2bf(wk[(ci0 + i) * COUT + cout]);
        unsigned short* dst = wimg + (size_t)k * COUT * FS + cout * FS + ci0;
        *(u32x4*)dst       = pk.u[0];
        *(u32x4*)(dst + 8) = pk.u[1];
        if (k == 0 && tid < CIN) fb[(size_t)NVOX * CIN + tid] = 0;
    } else {
        int t = (bid - NB_F2B - NB_WP) * 256 + tid;
        int o = out_map[t];
        rank[t] = (o >= 0) ? atomicAdd(&counts[o], 1) : -1;
    }
}

__global__ void scan1_kernel(const int* __restrict__ counts, int* __restrict__ startv,
                             int* __restrict__ bsum) {
    __shared__ int sm[256];
    int gid = blockIdx.x * 256 + threadIdx.x;
    int v = counts[gid];
    sm[threadIdx.x] = v;
    __syncthreads();
    for (int off = 1; off < 256; off <<= 1) {
        int t = (threadIdx.x >= off) ? sm[threadIdx.x - off] : 0;
        __syncthreads();
        sm[threadIdx.x] += t;
        __syncthreads();
    }
    int incl = sm[threadIdx.x];
    startv[gid] = incl - v;
    if (threadIdx.x == 255) bsum[blockIdx.x] = incl;
}

__global__ void scan2_kernel(const int* __restrict__ bsum, int* __restrict__ boff) {
    __shared__ int sm[512];
    int v = bsum[threadIdx.x];
    sm[threadIdx.x] = v;
    __syncthreads();
    for (int off = 1; off < 512; off <<= 1) {
        int t = (threadIdx.x >= off) ? sm[threadIdx.x - off] : 0;
        __syncthreads();
        sm[threadIdx.x] += t;
        __syncthreads();
    }
    boff[threadIdx.x] = sm[threadIdx.x] - v;
    if (threadIdx.x == 511) boff[512] = sm[511];
}

__global__ __launch_bounds__(256) void conv4_kernel(
    const unsigned short* __restrict__ featbf,
    const unsigned short* __restrict__ wimg,
    const int* __restrict__ in_map,
    const int* __restrict__ out_map,
    const int* __restrict__ startv,
    const int* __restrict__ boff,
    const int* __restrict__ rank,
    unsigned short* __restrict__ Ybf)
{
    __shared__ unsigned short Fl[PPB * FS];
    __shared__ unsigned short Wt[COUT * FS];

    const int tid  = threadIdx.x;
    const int wave = tid >> 6;
    const int lane = tid & 63;
    const int k    = blockIdx.x >> 8;
    const int pb   = blockIdx.x & 255;
    const int base = k * PPAIR + pb * PPB;

    {
        const unsigned short* wsrc = wimg + (size_t)k * COUT * FS;
        for (int c = wave; c < 9; c += 4)
            __builtin_amdgcn_global_load_lds(
                (const __attribute__((address_space(1))) void*)(wsrc + c * 512 + lane * 8),
                (__attribute__((address_space(3))) void*)(&Wt[c * 512 + lane * 8]),
                16, 0, 0);
    }
    {
        const int row = tid >> 1;
        const int h   = tid & 1;
        int im = in_map[base + row];
        const u32x4* src = (const u32x4*)(featbf + (size_t)(im >= 0 ? im : NVOX) * CIN + h * 32);
        u32x4 v0 = src[0], v1 = src[1], v2 = src[2], v3 = src[3];
        u32x4* dst = (u32x4*)&Fl[row * FS + h * 32];
        dst[0] = v0; dst[1] = v1; dst[2] = v2; dst[3] = v3;
    }
    __syncthreads();

    const int r = lane & 15;
    const int g = lane >> 4;

    bf16x8 af[2][2];
    bf16x8 bfr[4][2];
#pragma unroll
    for (int m = 0; m < 2; ++m)
#pragma unroll
        for (int s = 0; s < 2; ++s)
            af[m][s] = *(const bf16x8*)&Fl[(wave * 32 + m * 16 + r) * FS + s * 32 + g * 8];
#pragma unroll
    for (int n = 0; n < 4; ++n)
#pragma unroll
        for (int s = 0; s < 2; ++s)
            bfr[n][s] = *(const bf16x8*)&Wt[(n * 16 + r) * FS + s * 32 + g * 8];

    f32x4 acc[2][4];
#pragma unroll
    for (int m = 0; m < 2; ++m)
#pragma unroll
        for (int n = 0; n < 4; ++n)
            acc[m][n] = (f32x4){0.f, 0.f, 0.f, 0.f};

#pragma unroll
    for (int s = 0; s < 2; ++s)
#pragma unroll
        for (int m = 0; m < 2; ++m)
#pragma unroll
            for (int n = 0; n < 4; ++n)
                acc[m][n] = __builtin_amdgcn_mfma_f32_16x16x32_bf16(
                    af[m][s], bfr[n][s], acc[m][n], 0, 0, 0);

#pragma unroll
    for (int m = 0; m < 2; ++m)
#pragma unroll
        for (int n = 0; n < 4; ++n)
#pragma unroll
            for (int j = 0; j < 4; ++j)
                Fl[(wave * 32 + m * 16 + g * 4 + j) * FS + n * 16 + r] = f2bf(acc[m][n][j]);

    {
        const int p = tid >> 1;
        const int h = tid & 1;
        int o = out_map[base + p];
        if (o >= 0) {
            int s = startv[o] + boff[o >> 8] + rank[base + p];
            const unsigned short* src = &Fl[p * FS + h * 32];
            u32x4* dst = (u32x4*)(Ybf + (size_t)s * COUT + h * 32);
            u32x4 v0 = *(const u32x4*)(src + 0);
            u32x4 v1 = *(const u32x4*)(src + 8);
            u32x4 v2 = *(const u32x4*)(src + 16);
            u32x4 v3 = *(const u32x4*)(src + 24);
            dst[0] = v0; dst[1] = v1; dst[2] = v2; dst[3] = v3;
        }
    }
}

__global__ __launch_bounds__(256) void gather_out_kernel(
    const unsigned short* __restrict__ Y,
    const int* __restrict__ startv,
    const int* __restrict__ boff,
    const float* __restrict__ bias,
    float* __restrict__ out)
{
    const int row  = blockIdx.x * 4 + (threadIdx.x >> 6);
    const int lane = threadIdx.x & 63;
    const int c4   = (lane & 15) * 4;
    const int grp  = lane >> 4;

    const int b0 = row >> 8;
    int s0 = startv[row] + boff[b0];
    int s1 = ((row + 1) & 255) ? (startv[row + 1] + boff[b0]) : boff[b0 + 1];

    float4 acc = {0.f, 0.f, 0.f, 0.f};
    for (int j = s0 + grp; j < s1; j += 4) {
        u32x2 v = *(const u32x2*)&Y[(size_t)j * COUT + c4];
        acc.x += bfbits2f(v.x & 0xffffu);
        acc.y += bfbits2f(v.x >> 16);
        acc.z += bfbits2f(v.y & 0xffffu);
        acc.w += bfbits2f(v.y >> 16);
    }
    acc.x += __shfl_xor(acc.x, 16); acc.y += __shfl_xor(acc.y, 16);
    acc.z += __shfl_xor(acc.z, 16); acc.w += __shfl_xor(acc.w, 16);
    acc.x += __shfl_xor(acc.x, 32); acc.y += __shfl_xor(acc.y, 32);
    acc.z += __shfl_xor(acc.z, 32); acc.w += __shfl_xor(acc.w, 32);

    if (grp == 0) {
        float4 b = *(const float4*)&bias[c4];
        float4 rv = {acc.x + b.x, acc.y + b.y, acc.z + b.z, acc.w + b.w};
        *(float4*)&out[(size_t)row * COUT + c4] = rv;
    }
}

// ================= tiny-ws fallback (atomic path) =================
__global__ void init_out_kernel(float* __restrict__ out, const float* __restrict__ bias) {
    int i = blockIdx.x * blockDim.x + threadIdx.x;
    float4 b = ((const float4*)bias)[i & 15];
    ((float4*)out)[i] = b;
}

__global__ __launch_bounds__(256) void conv_atomic_kernel(
    const float* __restrict__ features, const float* __restrict__ weight,
    const int* __restrict__ in_map, const int* __restrict__ out_map,
    float* __restrict__ out)
{
    __shared__ float Wl[CIN * COUT];
    __shared__ float Fl2[128 * 65];
    const int tid = threadIdx.x;
    const int k = blockIdx.x / (PPAIR / 128);
    const int pb = blockIdx.x % (PPAIR / 128);
    const int base = k * PPAIR + pb * 128;
    const float* wk = weight + k * CIN * COUT;
#pragma unroll
    for (int j = 0; j < 4; ++j) {
        int idx = (j * 256 + tid) * 4;
        *(float4*)&Wl[idx] = *(const float4*)&wk[idx];
    }
    const int lane = tid & 63;
    const int rsel = tid >> 6;
#pragma unroll 4
    for (int j = 0; j < 128; j += 4) {
        int row = j + rsel;
        int in_row = in_map[base + row];
        float v = 0.0f;
        if (in_row >= 0) v = features[in_row * CIN + lane];
        Fl2[row * 65 + lane] = v;
    }
    __syncthreads();
    const int cg = tid & 7;
    const int pg = tid >> 3;
    float acc[4][8];
#pragma unroll
    for (int a = 0; a < 4; ++a)
#pragma unroll
        for (int b = 0; b < 8; ++b) acc[a][b] = 0.0f;
    const float* wbase = &Wl[cg * 8];
    const float* fbase = &Fl2[pg * 4 * 65];
#pragma unroll 8
    for (int i = 0; i < CIN; ++i) {
        float4 w0 = *(const float4*)&wbase[i * 64];
        float4 w1 = *(const float4*)&wbase[i * 64 + 4];
        float wv[8] = {w0.x, w0.y, w0.z, w0.w, w1.x, w1.y, w1.z, w1.w};
        float fv[4];
#pragma unroll
        for (int a = 0; a < 4; ++a) fv[a] = fbase[a * 65 + i];
#pragma unroll
        for (int a = 0; a < 4; ++a)
#pragma unroll
            for (int b = 0; b < 8; ++b)
                acc[a][b] = fmaf(fv[a], wv[b], acc[a][b]);
    }
#pragma unroll
    for (int a = 0; a < 4; ++a) {
        int pair = pg * 4 + a;
        int orow = out_map[base + pair];
        if (orow >= 0) {
            float* dst = out + orow * COUT + cg * 8;
#pragma unroll
            for (int b = 0; b < 8; ++b) unsafeAtomicAdd(dst + b, acc[a][b]);
        }
    }
}

// ================= launch =================
extern "C" void kernel_launch(void* const* d_in, const int* in_sizes, int n_in,
                              void* d_out, int out_size, void* d_ws, size_t ws_size,
                              hipStream_t stream) {
    const float* features = (const float*)d_in[0];
    const float* weight   = (const float*)d_in[1];
    const float* bias     = (const float*)d_in[2];
    const int*   in_map   = (const int*)d_in[3];
    const int*   out_map  = (const int*)d_in[4];
    float*       out      = (float*)d_out;
    char* ws = (char*)d_ws;

    if (ws_size >= WS_CAP) {
        // ---- fixed-capacity bucket path (no hist/scan) ----
        unsigned short* Ybf  = (unsigned short*)(ws + YC_OFF);
        int* cursor  = (int*)(ws + CUR2_OFF);
        int* ovf_cnt = (int*)(ws + OVFC_OFF);
        int* ovf     = (int*)(ws + OVF_OFF);
        unsigned short* wimg = (unsigned short*)(ws + WIMG2_OFF);
        unsigned short* fb   = (unsigned short*)(ws + FB2_OFF);

        (void)hipMemsetAsync(cursor, 0, (size_t)NVOX * 4, stream);
        (void)hipMemsetAsync(ovf_cnt, 0, 256, stream);

        prep2_kernel<<<NB_F2B + NB_WP, 256, 0, stream>>>(features, fb, weight, wimg);
        conv5_kernel<<<KOFF * 256, 256, 0, stream>>>(
            fb, wimg, in_map, out_map, cursor, ovf_cnt, ovf, Ybf);
        gather_cap_kernel<<<NVOX / 4, 256, 0, stream>>>(Ybf, cursor, bias, out);
        fixup_kernel<<<8, 256, 0, stream>>>(fb, wimg, in_map, out_map, ovf_cnt, ovf, out);
        return;
    }

    if (ws_size >= WS_FULL) {
        // ---- counting-sort path (round-7) ----
        unsigned short* Ybf  = (unsigned short*)(ws + Y_OFF);
        int* rank   = (int*)(ws + RANK_OFF);
        int* counts = (int*)(ws + CNT_OFF);
        int* startv = (int*)(ws + START_OFF);
        int* bsum   = (int*)(ws + BSUM_OFF);
        int* boff   = (int*)(ws + BOFF_OFF);
        unsigned short* wimg = (unsigned short*)(ws + WIMG_OFF);
        unsigned short* fb   = (unsigned short*)(ws + FB_OFF);

        (void)hipMemsetAsync(counts, 0, (size_t)NVOX * 4, stream);
        prep_kernel<<<NB_F2B + NB_WP + NB_RNK, 256, 0, stream>>>(
            features, fb, weight, wimg, out_map, counts, rank);
        scan1_kernel<<<NVOX / 256, 256, 0, stream>>>(counts, startv, bsum);
        scan2_kernel<<<1, 512, 0, stream>>>(bsum, boff);
        conv4_kernel<<<KOFF * 256, 256, 0, stream>>>(
            fb, wimg, in_map, out_map, startv, boff, rank, Ybf);
        gather_out_kernel<<<NVOX / 4, 256, 0, stream>>>(Ybf, startv, boff, bias, out);
        return;
    }

    // ---- tiny-ws fallback ----
    int total4 = NVOX * COUT / 4;
    init_out_kernel<<<total4 / 256, 256, 0, stream>>>(out, bias);
    conv_atomic_kernel<<<KOFF * (PPAIR / 128), 256, 0, stream>>>(
        features, weight, in_map, out_map, out);
}

// Round 9
// 112.718 us; speedup vs baseline: 1.3822x; 1.3822x over previous
//
#include <hip/hip_runtime.h>
#include <hip/hip_bf16.h>

#define NVOX 131072
#define KOFF 27
#define PPAIR 32768
#define CIN 64
#define COUT 64
#define PPB 128          // pairs per conv block
#define FS 72            // padded bf16 stride (144 B)
#define TOTP (KOFF * PPAIR)
#define CAP 12           // slots per output row (fixed-capacity path)
#define OVF_MAX 32768

typedef __attribute__((ext_vector_type(8))) short bf16x8;
typedef __attribute__((ext_vector_type(4))) float f32x4;
typedef __attribute__((ext_vector_type(4))) unsigned int u32x4;
typedef __attribute__((ext_vector_type(2))) unsigned int u32x2;

static constexpr size_t WIMG_BYTES = (size_t)KOFF * COUT * FS * 2;      // 248832
static constexpr size_t FB_BYTES   = ((size_t)NVOX + 1) * CIN * 2;      // 16.78 MB

// ---- fixed-capacity (primary) workspace layout ----
static constexpr size_t YC_OFF    = 0;
static constexpr size_t YC_BYTES  = (size_t)NVOX * CAP * COUT * 2;      // 201.3 MB
static constexpr size_t CUR2_OFF  = YC_OFF + YC_BYTES;
static constexpr size_t OVFC_OFF  = CUR2_OFF + (size_t)NVOX * 4;
static constexpr size_t OVF_OFF   = OVFC_OFF + 256;
static constexpr size_t WIMG2_OFF = OVF_OFF + (size_t)OVF_MAX * 4;
static constexpr size_t FB2_OFF   = (WIMG2_OFF + WIMG_BYTES + 255) & ~(size_t)255;
static constexpr size_t WS_CAP    = FB2_OFF + FB_BYTES;                 // ~219 MB

// ---- counting-sort (mid-tier) workspace layout ----
static constexpr size_t Y_OFF     = 0;
static constexpr size_t Y_BYTES   = (size_t)TOTP * COUT * 2;            // 113.25 MB
static constexpr size_t RANK_OFF  = Y_OFF + Y_BYTES;
static constexpr size_t CNT_OFF   = RANK_OFF + (size_t)TOTP * 4;
static constexpr size_t START_OFF = CNT_OFF + (size_t)NVOX * 4;
static constexpr size_t BSUM_OFF  = START_OFF + ((size_t)NVOX + 64) * 4;
static constexpr size_t BOFF_OFF  = BSUM_OFF + 512 * 4;
static constexpr size_t WIMG_OFF  = BOFF_OFF + 520 * 4;
static constexpr size_t FB_OFF    = (WIMG_OFF + WIMG_BYTES + 255) & ~(size_t)255;
static constexpr size_t WS_FULL   = FB_OFF + FB_BYTES;                  // ~135 MB

__device__ __forceinline__ unsigned short f2bf(float f) {
    union { __hip_bfloat16 h; unsigned short u; } v;
    v.h = __float2bfloat16(f);
    return v.u;
}
__device__ __forceinline__ float bfbits2f(unsigned int u) {
    union { unsigned int i; float f; } v; v.i = u << 16; return v.f;
}
__device__ __forceinline__ float dot8(u32x4 a, u32x4 b) {
    float s = 0.f;
    s += bfbits2f(a.x & 0xffffu) * bfbits2f(b.x & 0xffffu);
    s += bfbits2f(a.x >> 16)     * bfbits2f(b.x >> 16);
    s += bfbits2f(a.y & 0xffffu) * bfbits2f(b.y & 0xffffu);
    s += bfbits2f(a.y >> 16)     * bfbits2f(b.y >> 16);
    s += bfbits2f(a.z & 0xffffu) * bfbits2f(b.z & 0xffffu);
    s += bfbits2f(a.z >> 16)     * bfbits2f(b.z >> 16);
    s += bfbits2f(a.w & 0xffffu) * bfbits2f(b.w & 0xffffu);
    s += bfbits2f(a.w >> 16)     * bfbits2f(b.w >> 16);
    return s;
}

#define NB_F2B 4096                       // NVOX*CIN/8/256
#define NB_WP  KOFF
#define NB_RNK (TOTP / 256)

// ================= prep2 (cap path): feat->bf16 | weight image, NO atomics =================
__global__ __launch_bounds__(256) void prep2_kernel(
    const float* __restrict__ f, unsigned short* __restrict__ fb,
    const float* __restrict__ w, unsigned short* __restrict__ wimg)
{
    const int bid = blockIdx.x;
    const int tid = threadIdx.x;
    if (bid < NB_F2B) {
        int i = bid * 256 + tid;
        float4 a = ((const float4*)f)[i * 2];
        float4 b = ((const float4*)f)[i * 2 + 1];
        union { u32x4 u; unsigned short s[8]; } pk;
        pk.s[0]=f2bf(a.x); pk.s[1]=f2bf(a.y); pk.s[2]=f2bf(a.z); pk.s[3]=f2bf(a.w);
        pk.s[4]=f2bf(b.x); pk.s[5]=f2bf(b.y); pk.s[6]=f2bf(b.z); pk.s[7]=f2bf(b.w);
        ((u32x4*)fb)[i] = pk.u;
    } else {
        const int k    = bid - NB_F2B;
        const int cout = tid & 63;
        const int ci0  = (tid >> 6) * 16;
        const float* wk = w + (size_t)k * CIN * COUT;
        union { u32x4 u[2]; unsigned short s[16]; } pk;
#pragma unroll
        for (int i = 0; i < 16; ++i)
            pk.s[i] = f2bf(wk[(ci0 + i) * COUT + cout]);
        unsigned short* dst = wimg + (size_t)k * COUT * FS + cout * FS + ci0;
        *(u32x4*)dst       = pk.u[0];
        *(u32x4*)(dst + 8) = pk.u[1];
        if (k == 0 && tid < CIN) fb[(size_t)NVOX * CIN + tid] = 0;  // zero row
    }
}

// ================= conv5 (cap path): gather -> MFMA -> bucketed-Y =================
__global__ __launch_bounds__(256) void conv5_kernel(
    const unsigned short* __restrict__ featbf,
    const unsigned short* __restrict__ wimg,     // [k][cout][ci] stride FS
    const int* __restrict__ in_map,
    const int* __restrict__ out_map,
    int* __restrict__ cursor,
    int* __restrict__ ovf_cnt,
    int* __restrict__ ovf,
    unsigned short* __restrict__ Ybf)
{
    __shared__ unsigned short Fl[PPB * FS];     // 18432 B
    __shared__ unsigned short Wt[COUT * FS];    //  9216 B

    const int tid  = threadIdx.x;
    const int wave = tid >> 6;
    const int lane = tid & 63;
    const int k    = blockIdx.x >> 8;
    const int pb   = blockIdx.x & 255;
    const int base = k * PPAIR + pb * PPB;

    // ---- EARLY slot assignment: atomic latency hides under staging+barrier+MFMA ----
    const int p = tid >> 1;
    const int h = tid & 1;
    int slot = -1;
    {
        int o = out_map[base + p];
        if (h == 0 && o >= 0) {
            int r0 = atomicAdd(&cursor[o], 1);
            if (r0 < CAP) {
                slot = o * CAP + r0;
            } else {
                int idx = atomicAdd(ovf_cnt, 1);
                if (idx < OVF_MAX) ovf[idx] = base + p;
            }
        }
    }

    // ---- stage Wt (9216 B = 9 chunks of 1 KiB) ----
    {
        const unsigned short* wsrc = wimg + (size_t)k * COUT * FS;
        for (int c = wave; c < 9; c += 4)
            __builtin_amdgcn_global_load_lds(
                (const __attribute__((address_space(1))) void*)(wsrc + c * 512 + lane * 8),
                (__attribute__((address_space(3))) void*)(&Wt[c * 512 + lane * 8]),
                16, 0, 0);
    }

    // ---- branchless gather: 2 threads/row, 64 B each ----
    {
        int im = in_map[base + p];
        const u32x4* src = (const u32x4*)(featbf + (size_t)(im >= 0 ? im : NVOX) * CIN + h * 32);
        u32x4 v0 = src[0], v1 = src[1], v2 = src[2], v3 = src[3];
        u32x4* dst = (u32x4*)&Fl[p * FS + h * 32];
        dst[0] = v0; dst[1] = v1; dst[2] = v2; dst[3] = v3;
    }

    // share slot with partner thread before the barrier
    slot = __shfl(slot, lane & 62);

    __syncthreads();

    // ---- MFMA: wave computes 32 pairs x 64 couts ----
    const int r = lane & 15;
    const int g = lane >> 4;

    bf16x8 af[2][2];
    bf16x8 bfr[4][2];
#pragma unroll
    for (int m = 0; m < 2; ++m)
#pragma unroll
        for (int s = 0; s < 2; ++s)
            af[m][s] = *(const bf16x8*)&Fl[(wave * 32 + m * 16 + r) * FS + s * 32 + g * 8];
#pragma unroll
    for (int n = 0; n < 4; ++n)
#pragma unroll
        for (int s = 0; s < 2; ++s)
            bfr[n][s] = *(const bf16x8*)&Wt[(n * 16 + r) * FS + s * 32 + g * 8];

    f32x4 acc[2][4];
#pragma unroll
    for (int m = 0; m < 2; ++m)
#pragma unroll
        for (int n = 0; n < 4; ++n)
            acc[m][n] = (f32x4){0.f, 0.f, 0.f, 0.f};

#pragma unroll
    for (int s = 0; s < 2; ++s)
#pragma unroll
        for (int m = 0; m < 2; ++m)
#pragma unroll
            for (int n = 0; n < 4; ++n)
                acc[m][n] = __builtin_amdgcn_mfma_f32_16x16x32_bf16(
                    af[m][s], bfr[n][s], acc[m][n], 0, 0, 0);

    // ---- stage C (bf16) into wave-private Fl rows ----
#pragma unroll
    for (int m = 0; m < 2; ++m)
#pragma unroll
        for (int n = 0; n < 4; ++n)
#pragma unroll
            for (int j = 0; j < 4; ++j)
                Fl[(wave * 32 + m * 16 + g * 4 + j) * FS + n * 16 + r] = f2bf(acc[m][n][j]);

    // ---- copy out with precomputed slot ----
    if (slot >= 0) {
        const unsigned short* src = &Fl[p * FS + h * 32];
        u32x4* dst = (u32x4*)(Ybf + (size_t)slot * COUT + h * 32);
        u32x4 v0 = *(const u32x4*)(src + 0);
        u32x4 v1 = *(const u32x4*)(src + 8);
        u32x4 v2 = *(const u32x4*)(src + 16);
        u32x4 v3 = *(const u32x4*)(src + 24);
        dst[0] = v0; dst[1] = v1; dst[2] = v2; dst[3] = v3;
    }
}

// ================= gather (cap path) =================
__global__ __launch_bounds__(256) void gather_cap_kernel(
    const unsigned short* __restrict__ Y,
    const int* __restrict__ cursor,
    const float* __restrict__ bias,
    float* __restrict__ out)
{
    const int row  = blockIdx.x * 4 + (threadIdx.x >> 6);
    const int lane = threadIdx.x & 63;
    const int c4   = (lane & 15) * 4;
    const int grp  = lane >> 4;

    int cnt = cursor[row];
    if (cnt > CAP) cnt = CAP;
    const unsigned short* yb = Y + (size_t)row * CAP * COUT;

    float4 acc = {0.f, 0.f, 0.f, 0.f};
    for (int j = grp; j < cnt; j += 4) {
        u32x2 v = *(const u32x2*)&yb[j * COUT + c4];
        acc.x += bfbits2f(v.x & 0xffffu);
        acc.y += bfbits2f(v.x >> 16);
        acc.z += bfbits2f(v.y & 0xffffu);
        acc.w += bfbits2f(v.y >> 16);
    }
    acc.x += __shfl_xor(acc.x, 16); acc.y += __shfl_xor(acc.y, 16);
    acc.z += __shfl_xor(acc.z, 16); acc.w += __shfl_xor(acc.w, 16);
    acc.x += __shfl_xor(acc.x, 32); acc.y += __shfl_xor(acc.y, 32);
    acc.z += __shfl_xor(acc.z, 32); acc.w += __shfl_xor(acc.w, 32);

    if (grp == 0) {
        float4 b = *(const float4*)&bias[c4];
        float4 rv = {acc.x + b.x, acc.y + b.y, acc.z + b.z, acc.w + b.w};
        *(float4*)&out[(size_t)row * COUT + c4] = rv;
    }
}

// ================= overflow fixup: one WAVE per entry, wide grid =================
__global__ __launch_bounds__(256) void fixup_kernel(
    const unsigned short* __restrict__ fb,
    const unsigned short* __restrict__ wimg,
    const int* __restrict__ in_map,
    const int* __restrict__ out_map,
    const int* __restrict__ ovf_cnt,
    const int* __restrict__ ovf,
    float* __restrict__ out)
{
    int n = ovf_cnt[0];
    if (n > OVF_MAX) n = OVF_MAX;
    const int lane = threadIdx.x & 63;
    const int wid  = (blockIdx.x * 256 + threadIdx.x) >> 6;
    const int nw   = (gridDim.x * 256) >> 6;
    for (int e = wid; e < n; e += nw) {
        int t  = ovf[e];
        int k  = t >> 15;                 // t / PPAIR
        int in = in_map[t];
        int o  = out_map[t];
        const u32x4* fr = (const u32x4*)(fb + (size_t)in * CIN);            // broadcast
        const unsigned short* wr = wimg + (size_t)k * COUT * FS + lane * FS;
        float acc = 0.f;
#pragma unroll
        for (int c8 = 0; c8 < 8; ++c8)
            acc += dot8(fr[c8], *(const u32x4*)(wr + c8 * 8));
        unsafeAtomicAdd(out + (size_t)o * COUT + lane, acc);
    }
}

// ================= counting-sort mid-tier (round-7 verified path) =================
__global__ __launch_bounds__(256) void prep_kernel(
    const float* __restrict__ f, unsigned short* __restrict__ fb,
    const float* __restrict__ w, unsigned short* __restrict__ wimg,
    const int* __restrict__ out_map, int* __restrict__ counts,
    int* __restrict__ rank)
{
    const int bid = blockIdx.x;
    const int tid = threadIdx.x;
    if (bid < NB_F2B) {
        int i = bid * 256 + tid;
        float4 a = ((const float4*)f)[i * 2];
        float4 b = ((const float4*)f)[i * 2 + 1];
        union { u32x4 u; unsigned short s[8]; } pk;
        pk.s[0]=f2bf(a.x); pk.s[1]=f2bf(a.y); pk.s[2]=f2bf(a.z); pk.s[3]=f2bf(a.w);
        pk.s[4]=f2bf(b.x); pk.s[5]=f2bf(b.y); pk.s[6]=f2bf(b.z); pk.s[7]=f2bf(b.w);
        ((u32x4*)fb)[i] = pk.u;
    } else if (bid < NB_F2B + NB_WP) {
        const int k    = bid - NB_F2B;
        const int cout = tid & 63;
        const int ci0  = (tid >> 6) * 16;
        const float* wk = w + (size_t)k * CIN * COUT;
        union { u32x4 u[2]; unsigned short s[16]; } pk;
#pragma unroll
        for (int i = 0; i < 16; ++i)
            pk.s[i] = f2bf(wk[(ci0 + i) * COUT + cout]);
        unsigned short* dst = wimg + (size_t)k * COUT * FS + cout * FS + ci0;
        *(u32x4*)dst       = pk.u[0];
        *(u32x4*)(dst + 8) = pk.u[1];
        if (k == 0 && tid < CIN) fb[(size_t)NVOX * CIN + tid] = 0;
    } else {
        int t = (bid - NB_F2B - NB_WP) * 256 + tid;
        int o = out_map[t];
        rank[t] = (o >= 0) ? atomicAdd(&counts[o], 1) : -1;
    }
}

__global__ void scan1_kernel(const int* __restrict__ counts, int* __restrict__ startv,
                             int* __restrict__ bsum) {
    __shared__ int sm[256];
    int gid = blockIdx.x * 256 + threadIdx.x;
    int v = counts[gid];
    sm[threadIdx.x] = v;
    __syncthreads();
    for (int off = 1; off < 256; off <<= 1) {
        int t = (threadIdx.x >= off) ? sm[threadIdx.x - off] : 0;
        __syncthreads();
        sm[threadIdx.x] += t;
        __syncthreads();
    }
    int incl = sm[threadIdx.x];
    startv[gid] = incl - v;
    if (threadIdx.x == 255) bsum[blockIdx.x] = incl;
}

__global__ void scan2_kernel(const int* __restrict__ bsum, int* __restrict__ boff) {
    __shared__ int sm[512];
    int v = bsum[threadIdx.x];
    sm[threadIdx.x] = v;
    __syncthreads();
    for (int off = 1; off < 512; off <<= 1) {
        int t = (threadIdx.x >= off) ? sm[threadIdx.x - off] : 0;
        __syncthreads();
        sm[threadIdx.x] += t;
        __syncthreads();
    }
    boff[threadIdx.x] = sm[threadIdx.x] - v;
    if (threadIdx.x == 511) boff[512] = sm[511];
}

__global__ __launch_bounds__(256) void conv4_kernel(
    const unsigned short* __restrict__ featbf,
    const unsigned short* __restrict__ wimg,
    const int* __restrict__ in_map,
    const int* __restrict__ out_map,
    const int* __restrict__ startv,
    const int* __restrict__ boff,
    const int* __restrict__ rank,
    unsigned short* __restrict__ Ybf)
{
    __shared__ unsigned short Fl[PPB * FS];
    __shared__ unsigned short Wt[COUT * FS];

    const int tid  = threadIdx.x;
    const int wave = tid >> 6;
    const int lane = tid & 63;
    const int k    = blockIdx.x >> 8;
    const int pb   = blockIdx.x & 255;
    const int base = k * PPAIR + pb * PPB;

    {
        const unsigned short* wsrc = wimg + (size_t)k * COUT * FS;
        for (int c = wave; c < 9; c += 4)
            __builtin_amdgcn_global_load_lds(
                (const __attribute__((address_space(1))) void*)(wsrc + c * 512 + lane * 8),
                (__attribute__((address_space(3))) void*)(&Wt[c * 512 + lane * 8]),
                16, 0, 0);
    }
    {
        const int row = tid >> 1;
        const int h   = tid & 1;
        int im = in_map[base + row];
        const u32x4* src = (const u32x4*)(featbf + (size_t)(im >= 0 ? im : NVOX) * CIN + h * 32);
        u32x4 v0 = src[0], v1 = src[1], v2 = src[2], v3 = src[3];
        u32x4* dst = (u32x4*)&Fl[row * FS + h * 32];
        dst[0] = v0; dst[1] = v1; dst[2] = v2; dst[3] = v3;
    }
    __syncthreads();

    const int r = lane & 15;
    const int g = lane >> 4;

    bf16x8 af[2][2];
    bf16x8 bfr[4][2];
#pragma unroll
    for (int m = 0; m < 2; ++m)
#pragma unroll
        for (int s = 0; s < 2; ++s)
            af[m][s] = *(const bf16x8*)&Fl[(wave * 32 + m * 16 + r) * FS + s * 32 + g * 8];
#pragma unroll
    for (int n = 0; n < 4; ++n)
#pragma unroll
        for (int s = 0; s < 2; ++s)
            bfr[n][s] = *(const bf16x8*)&Wt[(n * 16 + r) * FS + s * 32 + g * 8];

    f32x4 acc[2][4];
#pragma unroll
    for (int m = 0; m < 2; ++m)
#pragma unroll
        for (int n = 0; n < 4; ++n)
            acc[m][n] = (f32x4){0.f, 0.f, 0.f, 0.f};

#pragma unroll
    for (int s = 0; s < 2; ++s)
#pragma unroll
        for (int m = 0; m < 2; ++m)
#pragma unroll
            for (int n = 0; n < 4; ++n)
                acc[m][n] = __builtin_amdgcn_mfma_f32_16x16x32_bf16(
                    af[m][s], bfr[n][s], acc[m][n], 0, 0, 0);

#pragma unroll
    for (int m = 0; m < 2; ++m)
#pragma unroll
        for (int n = 0; n < 4; ++n)
#pragma unroll
            for (int j = 0; j < 4; ++j)
                Fl[(wave * 32 + m * 16 + g * 4 + j) * FS + n * 16 + r] = f2bf(acc[m][n][j]);

    {
        const int p = tid >> 1;
        const int h = tid & 1;
        int o = out_map[base + p];
        if (o >= 0) {
            int s = startv[o] + boff[o >> 8] + rank[base + p];
            const unsigned short* src = &Fl[p * FS + h * 32];
            u32x4* dst = (u32x4*)(Ybf + (size_t)s * COUT + h * 32);
            u32x4 v0 = *(const u32x4*)(src + 0);
            u32x4 v1 = *(const u32x4*)(src + 8);
            u32x4 v2 = *(const u32x4*)(src + 16);
            u32x4 v3 = *(const u32x4*)(src + 24);
            dst[0] = v0; dst[1] = v1; dst[2] = v2; dst[3] = v3;
        }
    }
}

__global__ __launch_bounds__(256) void gather_out_kernel(
    const unsigned short* __restrict__ Y,
    const int* __restrict__ startv,
    const int* __restrict__ boff,
    const float* __restrict__ bias,
    float* __restrict__ out)
{
    const int row  = blockIdx.x * 4 + (threadIdx.x >> 6);
    const int lane = threadIdx.x & 63;
    const int c4   = (lane & 15) * 4;
    const int grp  = lane >> 4;

    const int b0 = row >> 8;
    int s0 = startv[row] + boff[b0];
    int s1 = ((row + 1) & 255) ? (startv[row + 1] + boff[b0]) : boff[b0 + 1];

    float4 acc = {0.f, 0.f, 0.f, 0.f};
    for (int j = s0 + grp; j < s1; j += 4) {
        u32x2 v = *(const u32x2*)&Y[(size_t)j * COUT + c4];
        acc.x += bfbits2f(v.x & 0xffffu);
        acc.y += bfbits2f(v.x >> 16);
        acc.z += bfbits2f(v.y & 0xffffu);
        acc.w += bfbits2f(v.y >> 16);
    }
    acc.x += __shfl_xor(acc.x, 16); acc.y += __shfl_xor(acc.y, 16);
    acc.z += __shfl_xor(acc.z, 16); acc.w += __shfl_xor(acc.w, 16);
    acc.x += __shfl_xor(acc.x, 32); acc.y += __shfl_xor(acc.y, 32);
    acc.z += __shfl_xor(acc.z, 32); acc.w += __shfl_xor(acc.w, 32);

    if (grp == 0) {
        float4 b = *(const float4*)&bias[c4];
        float4 rv = {acc.x + b.x, acc.y + b.y, acc.z + b.z, acc.w + b.w};
        *(float4*)&out[(size_t)row * COUT + c4] = rv;
    }
}

// ================= tiny-ws fallback (atomic path) =================
__global__ void init_out_kernel(float* __restrict__ out, const float* __restrict__ bias) {
    int i = blockIdx.x * blockDim.x + threadIdx.x;
    float4 b = ((const float4*)bias)[i & 15];
    ((float4*)out)[i] = b;
}

__global__ __launch_bounds__(256) void conv_atomic_kernel(
    const float* __restrict__ features, const float* __restrict__ weight,
    const int* __restrict__ in_map, const int* __restrict__ out_map,
    float* __restrict__ out)
{
    __shared__ float Wl[CIN * COUT];
    __shared__ float Fl2[128 * 65];
    const int tid = threadIdx.x;
    const int k = blockIdx.x / (PPAIR / 128);
    const int pb = blockIdx.x % (PPAIR / 128);
    const int base = k * PPAIR + pb * 128;
    const float* wk = weight + k * CIN * COUT;
#pragma unroll
    for (int j = 0; j < 4; ++j) {
        int idx = (j * 256 + tid) * 4;
        *(float4*)&Wl[idx] = *(const float4*)&wk[idx];
    }
    const int lane = tid & 63;
    const int rsel = tid >> 6;
#pragma unroll 4
    for (int j = 0; j < 128; j += 4) {
        int row = j + rsel;
        int in_row = in_map[base + row];
        float v = 0.0f;
        if (in_row >= 0) v = features[in_row * CIN + lane];
        Fl2[row * 65 + lane] = v;
    }
    __syncthreads();
    const int cg = tid & 7;
    const int pg = tid >> 3;
    float acc[4][8];
#pragma unroll
    for (int a = 0; a < 4; ++a)
#pragma unroll
        for (int b = 0; b < 8; ++b) acc[a][b] = 0.0f;
    const float* wbase = &Wl[cg * 8];
    const float* fbase = &Fl2[pg * 4 * 65];
#pragma unroll 8
    for (int i = 0; i < CIN; ++i) {
        float4 w0 = *(const float4*)&wbase[i * 64];
        float4 w1 = *(const float4*)&wbase[i * 64 + 4];
        float wv[8] = {w0.x, w0.y, w0.z, w0.w, w1.x, w1.y, w1.z, w1.w};
        float fv[4];
#pragma unroll
        for (int a = 0; a < 4; ++a) fv[a] = fbase[a * 65 + i];
#pragma unroll
        for (int a = 0; a < 4; ++a)
#pragma unroll
            for (int b = 0; b < 8; ++b)
                acc[a][b] = fmaf(fv[a], wv[b], acc[a][b]);
    }
#pragma unroll
    for (int a = 0; a < 4; ++a) {
        int pair = pg * 4 + a;
        int orow = out_map[base + pair];
        if (orow >= 0) {
            float* dst = out + orow * COUT + cg * 8;
#pragma unroll
            for (int b = 0; b < 8; ++b) unsafeAtomicAdd(dst + b, acc[a][b]);
        }
    }
}

// ================= launch =================
extern "C" void kernel_launch(void* const* d_in, const int* in_sizes, int n_in,
                              void* d_out, int out_size, void* d_ws, size_t ws_size,
                              hipStream_t stream) {
    const float* features = (const float*)d_in[0];
    const float* weight   = (const float*)d_in[1];
    const float* bias     = (const float*)d_in[2];
    const int*   in_map   = (const int*)d_in[3];
    const int*   out_map  = (const int*)d_in[4];
    float*       out      = (float*)d_out;
    char* ws = (char*)d_ws;

    if (ws_size >= WS_CAP) {
        // ---- fixed-capacity bucket path (no hist/scan) ----
        unsigned short* Ybf  = (unsigned short*)(ws + YC_OFF);
        int* cursor  = (int*)(ws + CUR2_OFF);
        int* ovf_cnt = (int*)(ws + OVFC_OFF);
        int* ovf     = (int*)(ws + OVF_OFF);
        unsigned short* wimg = (unsigned short*)(ws + WIMG2_OFF);
        unsigned short* fb   = (unsigned short*)(ws + FB2_OFF);

        (void)hipMemsetAsync(cursor, 0, (size_t)NVOX * 4, stream);
        (void)hipMemsetAsync(ovf_cnt, 0, 256, stream);

        prep2_kernel<<<NB_F2B + NB_WP, 256, 0, stream>>>(features, fb, weight, wimg);
        conv5_kernel<<<KOFF * 256, 256, 0, stream>>>(
            fb, wimg, in_map, out_map, cursor, ovf_cnt, ovf, Ybf);
        gather_cap_kernel<<<NVOX / 4, 256, 0, stream>>>(Ybf, cursor, bias, out);
        fixup_kernel<<<256, 256, 0, stream>>>(fb, wimg, in_map, out_map, ovf_cnt, ovf, out);
        return;
    }

    if (ws_size >= WS_FULL) {
        // ---- counting-sort path (round-7) ----
        unsigned short* Ybf  = (unsigned short*)(ws + Y_OFF);
        int* rank   = (int*)(ws + RANK_OFF);
        int* counts = (int*)(ws + CNT_OFF);
        int* startv = (int*)(ws + START_OFF);
        int* bsum   = (int*)(ws + BSUM_OFF);
        int* boff   = (int*)(ws + BOFF_OFF);
        unsigned short* wimg = (unsigned short*)(ws + WIMG_OFF);
        unsigned short* fb   = (unsigned short*)(ws + FB_OFF);

        (void)hipMemsetAsync(counts, 0, (size_t)NVOX * 4, stream);
        prep_kernel<<<NB_F2B + NB_WP + NB_RNK, 256, 0, stream>>>(
            features, fb, weight, wimg, out_map, counts, rank);
        scan1_kernel<<<NVOX / 256, 256, 0, stream>>>(counts, startv, bsum);
        scan2_kernel<<<1, 512, 0, stream>>>(bsum, boff);
        conv4_kernel<<<KOFF * 256, 256, 0, stream>>>(
            fb, wimg, in_map, out_map, startv, boff, rank, Ybf);
        gather_out_kernel<<<NVOX / 4, 256, 0, stream>>>(Ybf, startv, boff, bias, out);
        return;
    }

    // ---- tiny-ws fallback ----
    int total4 = NVOX * COUT / 4;
    init_out_kernel<<<total4 / 256, 256, 0, stream>>>(out, bias);
    conv_atomic_kernel<<<KOFF * (PPAIR / 128), 256, 0, stream>>>(
        features, weight, in_map, out_map, out);
}

// Round 10
// 99.710 us; speedup vs baseline: 1.5625x; 1.1305x over previous
//
#include <hip/hip_runtime.h>
#include <hip/hip_bf16.h>

#define NVOX 131072
#define KOFF 27
#define PPAIR 32768
#define CIN 64
#define COUT 64
#define PPB 128          // pairs per conv block
#define FS 72            // padded bf16 stride (144 B) for Fl
#define TOTP (KOFF * PPAIR)
#define CAP 12           // slots per output row (fixed-capacity path)
#define OVF_MAX 32768

typedef __attribute__((ext_vector_type(8))) short bf16x8;
typedef __attribute__((ext_vector_type(4))) float f32x4;
typedef __attribute__((ext_vector_type(4))) unsigned int u32x4;
typedef __attribute__((ext_vector_type(2))) unsigned int u32x2;

static constexpr size_t WIMG_BYTES = (size_t)KOFF * COUT * FS * 2;      // 248832 (>= 27*8192)
static constexpr size_t FB_BYTES   = ((size_t)NVOX + 1) * CIN * 2;      // 16.78 MB

// ---- fixed-capacity (primary) workspace layout ----
static constexpr size_t YC_OFF    = 0;
static constexpr size_t YC_BYTES  = (size_t)NVOX * CAP * COUT * 2;      // 201.3 MB
static constexpr size_t CUR2_OFF  = YC_OFF + YC_BYTES;
static constexpr size_t OVFC_OFF  = CUR2_OFF + (size_t)NVOX * 4;
static constexpr size_t OVF_OFF   = OVFC_OFF + 256;
static constexpr size_t WIMG2_OFF = OVF_OFF + (size_t)OVF_MAX * 4;
static constexpr size_t FB2_OFF   = (WIMG2_OFF + WIMG_BYTES + 255) & ~(size_t)255;
static constexpr size_t WS_CAP    = FB2_OFF + FB_BYTES;                 // ~219 MB

// ---- counting-sort (mid-tier) workspace layout ----
static constexpr size_t Y_OFF     = 0;
static constexpr size_t Y_BYTES   = (size_t)TOTP * COUT * 2;            // 113.25 MB
static constexpr size_t RANK_OFF  = Y_OFF + Y_BYTES;
static constexpr size_t CNT_OFF   = RANK_OFF + (size_t)TOTP * 4;
static constexpr size_t START_OFF = CNT_OFF + (size_t)NVOX * 4;
static constexpr size_t BSUM_OFF  = START_OFF + ((size_t)NVOX + 64) * 4;
static constexpr size_t BOFF_OFF  = BSUM_OFF + 512 * 4;
static constexpr size_t WIMG_OFF  = BOFF_OFF + 520 * 4;
static constexpr size_t FB_OFF    = (WIMG_OFF + WIMG_BYTES + 255) & ~(size_t)255;
static constexpr size_t WS_FULL   = FB_OFF + FB_BYTES;                  // ~135 MB

__device__ __forceinline__ unsigned short f2bf(float f) {
    union { __hip_bfloat16 h; unsigned short u; } v;
    v.h = __float2bfloat16(f);
    return v.u;
}
__device__ __forceinline__ float bfbits2f(unsigned int u) {
    union { unsigned int i; float f; } v; v.i = u << 16; return v.f;
}
__device__ __forceinline__ float dot8(u32x4 a, u32x4 b) {
    float s = 0.f;
    s += bfbits2f(a.x & 0xffffu) * bfbits2f(b.x & 0xffffu);
    s += bfbits2f(a.x >> 16)     * bfbits2f(b.x >> 16);
    s += bfbits2f(a.y & 0xffffu) * bfbits2f(b.y & 0xffffu);
    s += bfbits2f(a.y >> 16)     * bfbits2f(b.y >> 16);
    s += bfbits2f(a.z & 0xffffu) * bfbits2f(b.z & 0xffffu);
    s += bfbits2f(a.z >> 16)     * bfbits2f(b.z >> 16);
    s += bfbits2f(a.w & 0xffffu) * bfbits2f(b.w & 0xffffu);
    s += bfbits2f(a.w >> 16)     * bfbits2f(b.w >> 16);
    return s;
}

#define NB_F2B 4096                       // NVOX*CIN/8/256
#define NB_WP  KOFF
#define NB_RNK (TOTP / 256)

// ================= prep2 (cap path): feat->bf16 | wimg2 | zero cursor/ovf =================
// wimg2[k]: 512 slots of 8 bf16; slot ((n*2+s)*64 + lane) holds
//   W[k][ci = s*32 + (lane>>4)*8 + j][cout = n*16 + (lane&15)], j=0..7
__global__ __launch_bounds__(256) void prep2_kernel(
    const float* __restrict__ f, unsigned short* __restrict__ fb,
    const float* __restrict__ w, unsigned short* __restrict__ wimg2,
    int* __restrict__ cursor, int* __restrict__ ovf_cnt)
{
    const int bid = blockIdx.x;
    const int tid = threadIdx.x;
    if (bid < NB_F2B) {
        int i = bid * 256 + tid;
        // fold cursor/ovf zeroing into the first blocks (replaces 2 memsets)
        if (bid < 128) ((u32x4*)cursor)[i] = (u32x4){0, 0, 0, 0};
        if (bid == 128 && tid == 0) ovf_cnt[0] = 0;
        float4 a = ((const float4*)f)[i * 2];
        float4 b = ((const float4*)f)[i * 2 + 1];
        union { u32x4 u; unsigned short s[8]; } pk;
        pk.s[0]=f2bf(a.x); pk.s[1]=f2bf(a.y); pk.s[2]=f2bf(a.z); pk.s[3]=f2bf(a.w);
        pk.s[4]=f2bf(b.x); pk.s[5]=f2bf(b.y); pk.s[6]=f2bf(b.z); pk.s[7]=f2bf(b.w);
        ((u32x4*)fb)[i] = pk.u;
    } else {
        const int k = bid - NB_F2B;
        const int n = tid >> 6;
        const int l = tid & 63;
        const int r = l & 15;
        const int g = l >> 4;
        const int cout = n * 16 + r;
        const float* wk = w + (size_t)k * CIN * COUT;
#pragma unroll
        for (int s = 0; s < 2; ++s) {
            const int ci0 = s * 32 + g * 8;
            union { u32x4 u; unsigned short sh[8]; } pk;
#pragma unroll
            for (int j = 0; j < 8; ++j)
                pk.sh[j] = f2bf(wk[(ci0 + j) * COUT + cout]);
            *(u32x4*)(wimg2 + (size_t)k * 4096 + ((n * 2 + s) * 64 + l) * 8) = pk.u;
        }
        if (k == 0 && tid < CIN) fb[(size_t)NVOX * CIN + tid] = 0;  // zero row
    }
}

// ================= conv6 (cap path): gather -> MFMA (global B-frags) -> bucketed-Y =================
__global__ __launch_bounds__(256, 6) void conv6_kernel(
    const unsigned short* __restrict__ featbf,
    const unsigned short* __restrict__ wimg2,
    const int* __restrict__ in_map,
    const int* __restrict__ out_map,
    int* __restrict__ cursor,
    int* __restrict__ ovf_cnt,
    int* __restrict__ ovf,
    unsigned short* __restrict__ Ybf)
{
    __shared__ unsigned short Fl[PPB * FS];     // 18432 B only -> high occupancy

    const int tid  = threadIdx.x;
    const int wave = tid >> 6;
    const int lane = tid & 63;
    const int k    = blockIdx.x >> 8;
    const int pb   = blockIdx.x & 255;
    const int base = k * PPAIR + pb * PPB;

    const int p = tid >> 1;
    const int h = tid & 1;

    // ---- map loads + branchless gather (in flight early) ----
    int im = in_map[base + p];
    int o  = out_map[base + p];
    const u32x4* src = (const u32x4*)(featbf + (size_t)(im >= 0 ? im : NVOX) * CIN + h * 32);
    u32x4 v0 = src[0], v1 = src[1], v2 = src[2], v3 = src[3];

    // ---- slot assignment (throughput cost; overlaps gather) ----
    int slot = -1;
    if (h == 0 && o >= 0) {
        int r0 = atomicAdd(&cursor[o], 1);
        if (r0 < CAP) {
            slot = o * CAP + r0;
        } else {
            int idx = atomicAdd(ovf_cnt, 1);
            if (idx < OVF_MAX) ovf[idx] = base + p;
        }
    }
    slot = __shfl(slot, lane & 62);

    {
        u32x4* dst = (u32x4*)&Fl[p * FS + h * 32];
        dst[0] = v0; dst[1] = v1; dst[2] = v2; dst[3] = v3;
    }
    __syncthreads();

    // ---- MFMA: wave computes 32 pairs x 64 couts; B-frags direct from L2 ----
    const int r = lane & 15;
    const int g = lane >> 4;

    bf16x8 af[2][2];
#pragma unroll
    for (int m = 0; m < 2; ++m)
#pragma unroll
        for (int s = 0; s < 2; ++s)
            af[m][s] = *(const bf16x8*)&Fl[(wave * 32 + m * 16 + r) * FS + s * 32 + g * 8];

    const unsigned short* wk2 = wimg2 + (size_t)k * 4096 + (size_t)lane * 8;

    f32x4 acc[2][4];
#pragma unroll
    for (int m = 0; m < 2; ++m)
#pragma unroll
        for (int n = 0; n < 4; ++n)
            acc[m][n] = (f32x4){0.f, 0.f, 0.f, 0.f};

#pragma unroll
    for (int s = 0; s < 2; ++s)
#pragma unroll
        for (int n = 0; n < 4; ++n) {
            bf16x8 b = *(const bf16x8*)(wk2 + (size_t)(n * 2 + s) * 512);
#pragma unroll
            for (int m = 0; m < 2; ++m)
                acc[m][n] = __builtin_amdgcn_mfma_f32_16x16x32_bf16(
                    af[m][s], b, acc[m][n], 0, 0, 0);
        }

    // ---- stage C (bf16) into wave-private Fl rows ----
#pragma unroll
    for (int m = 0; m < 2; ++m)
#pragma unroll
        for (int n = 0; n < 4; ++n)
#pragma unroll
            for (int j = 0; j < 4; ++j)
                Fl[(wave * 32 + m * 16 + g * 4 + j) * FS + n * 16 + r] = f2bf(acc[m][n][j]);

    // ---- copy out with precomputed slot ----
    if (slot >= 0) {
        const unsigned short* csrc = &Fl[p * FS + h * 32];
        u32x4* dst = (u32x4*)(Ybf + (size_t)slot * COUT + h * 32);
        u32x4 w0 = *(const u32x4*)(csrc + 0);
        u32x4 w1 = *(const u32x4*)(csrc + 8);
        u32x4 w2 = *(const u32x4*)(csrc + 16);
        u32x4 w3 = *(const u32x4*)(csrc + 24);
        dst[0] = w0; dst[1] = w1; dst[2] = w2; dst[3] = w3;
    }
}

// ================= gather (cap path) =================
__global__ __launch_bounds__(256) void gather_cap_kernel(
    const unsigned short* __restrict__ Y,
    const int* __restrict__ cursor,
    const float* __restrict__ bias,
    float* __restrict__ out)
{
    const int row  = blockIdx.x * 4 + (threadIdx.x >> 6);
    const int lane = threadIdx.x & 63;
    const int c4   = (lane & 15) * 4;
    const int grp  = lane >> 4;

    int cnt = cursor[row];
    if (cnt > CAP) cnt = CAP;
    const unsigned short* yb = Y + (size_t)row * CAP * COUT;

    float4 acc = {0.f, 0.f, 0.f, 0.f};
    for (int j = grp; j < cnt; j += 4) {
        u32x2 v = *(const u32x2*)&yb[j * COUT + c4];
        acc.x += bfbits2f(v.x & 0xffffu);
        acc.y += bfbits2f(v.x >> 16);
        acc.z += bfbits2f(v.y & 0xffffu);
        acc.w += bfbits2f(v.y >> 16);
    }
    acc.x += __shfl_xor(acc.x, 16); acc.y += __shfl_xor(acc.y, 16);
    acc.z += __shfl_xor(acc.z, 16); acc.w += __shfl_xor(acc.w, 16);
    acc.x += __shfl_xor(acc.x, 32); acc.y += __shfl_xor(acc.y, 32);
    acc.z += __shfl_xor(acc.z, 32); acc.w += __shfl_xor(acc.w, 32);

    if (grp == 0) {
        float4 b = *(const float4*)&bias[c4];
        float4 rv = {acc.x + b.x, acc.y + b.y, acc.z + b.z, acc.w + b.w};
        *(float4*)&out[(size_t)row * COUT + c4] = rv;
    }
}

// ================= overflow fixup: one wave per entry =================
__global__ __launch_bounds__(256) void fixup_kernel(
    const unsigned short* __restrict__ fb,
    const unsigned short* __restrict__ wimg2,
    const int* __restrict__ in_map,
    const int* __restrict__ out_map,
    const int* __restrict__ ovf_cnt,
    const int* __restrict__ ovf,
    float* __restrict__ out)
{
    int n = ovf_cnt[0];
    if (n > OVF_MAX) n = OVF_MAX;
    const int lane = threadIdx.x & 63;
    const int wid  = (blockIdx.x * 256 + threadIdx.x) >> 6;
    const int nw   = (gridDim.x * 256) >> 6;
    const int nn   = lane >> 4;           // cout = nn*16 + rr
    const int rr   = lane & 15;
    for (int e = wid; e < n; e += nw) {
        int t  = ovf[e];
        int k  = t >> 15;                 // t / PPAIR
        int in = in_map[t];
        int o  = out_map[t];
        const u32x4* fr = (const u32x4*)(fb + (size_t)in * CIN);
        const unsigned short* wk2 = wimg2 + (size_t)k * 4096;
        float acc = 0.f;
#pragma unroll
        for (int s = 0; s < 2; ++s)
#pragma unroll
            for (int g = 0; g < 4; ++g) {
                u32x4 wc = *(const u32x4*)(wk2 + ((nn * 2 + s) * 64 + g * 16 + rr) * 8);
                acc += dot8(fr[s * 4 + g], wc);
            }
        unsafeAtomicAdd(out + (size_t)o * COUT + lane, acc);
    }
}

// ================= counting-sort mid-tier (round-7 verified path) =================
__global__ __launch_bounds__(256) void prep_kernel(
    const float* __restrict__ f, unsigned short* __restrict__ fb,
    const float* __restrict__ w, unsigned short* __restrict__ wimg,
    const int* __restrict__ out_map, int* __restrict__ counts,
    int* __restrict__ rank)
{
    const int bid = blockIdx.x;
    const int tid = threadIdx.x;
    if (bid < NB_F2B) {
        int i = bid * 256 + tid;
        float4 a = ((const float4*)f)[i * 2];
        float4 b = ((const float4*)f)[i * 2 + 1];
        union { u32x4 u; unsigned short s[8]; } pk;
        pk.s[0]=f2bf(a.x); pk.s[1]=f2bf(a.y); pk.s[2]=f2bf(a.z); pk.s[3]=f2bf(a.w);
        pk.s[4]=f2bf(b.x); pk.s[5]=f2bf(b.y); pk.s[6]=f2bf(b.z); pk.s[7]=f2bf(b.w);
        ((u32x4*)fb)[i] = pk.u;
    } else if (bid < NB_F2B + NB_WP) {
        const int k    = bid - NB_F2B;
        const int cout = tid & 63;
        const int ci0  = (tid >> 6) * 16;
        const float* wk = w + (size_t)k * CIN * COUT;
        union { u32x4 u[2]; unsigned short s[16]; } pk;
#pragma unroll
        for (int i = 0; i < 16; ++i)
            pk.s[i] = f2bf(wk[(ci0 + i) * COUT + cout]);
        unsigned short* dst = wimg + (size_t)k * COUT * FS + cout * FS + ci0;
        *(u32x4*)dst       = pk.u[0];
        *(u32x4*)(dst + 8) = pk.u[1];
        if (k == 0 && tid < CIN) fb[(size_t)NVOX * CIN + tid] = 0;
    } else {
        int t = (bid - NB_F2B - NB_WP) * 256 + tid;
        int o = out_map[t];
        rank[t] = (o >= 0) ? atomicAdd(&counts[o], 1) : -1;
    }
}

__global__ void scan1_kernel(const int* __restrict__ counts, int* __restrict__ startv,
                             int* __restrict__ bsum) {
    __shared__ int sm[256];
    int gid = blockIdx.x * 256 + threadIdx.x;
    int v = counts[gid];
    sm[threadIdx.x] = v;
    __syncthreads();
    for (int off = 1; off < 256; off <<= 1) {
        int t = (threadIdx.x >= off) ? sm[threadIdx.x - off] : 0;
        __syncthreads();
        sm[threadIdx.x] += t;
        __syncthreads();
    }
    int incl = sm[threadIdx.x];
    startv[gid] = incl - v;
    if (threadIdx.x == 255) bsum[blockIdx.x] = incl;
}

__global__ void scan2_kernel(const int* __restrict__ bsum, int* __restrict__ boff) {
    __shared__ int sm[512];
    int v = bsum[threadIdx.x];
    sm[threadIdx.x] = v;
    __syncthreads();
    for (int off = 1; off < 512; off <<= 1) {
        int t = (threadIdx.x >= off) ? sm[threadIdx.x - off] : 0;
        __syncthreads();
        sm[threadIdx.x] += t;
        __syncthreads();
    }
    boff[threadIdx.x] = sm[threadIdx.x] - v;
    if (threadIdx.x == 511) boff[512] = sm[511];
}

__global__ __launch_bounds__(256) void conv4_kernel(
    const unsigned short* __restrict__ featbf,
    const unsigned short* __restrict__ wimg,
    const int* __restrict__ in_map,
    const int* __restrict__ out_map,
    const int* __restrict__ startv,
    const int* __restrict__ boff,
    const int* __restrict__ rank,
    unsigned short* __restrict__ Ybf)
{
    __shared__ unsigned short Fl[PPB * FS];
    __shared__ unsigned short Wt[COUT * FS];

    const int tid  = threadIdx.x;
    const int wave = tid >> 6;
    const int lane = tid & 63;
    const int k    = blockIdx.x >> 8;
    const int pb   = blockIdx.x & 255;
    const int base = k * PPAIR + pb * PPB;

    {
        const unsigned short* wsrc = wimg + (size_t)k * COUT * FS;
        for (int c = wave; c < 9; c += 4)
            __builtin_amdgcn_global_load_lds(
                (const __attribute__((address_space(1))) void*)(wsrc + c * 512 + lane * 8),
                (__attribute__((address_space(3))) void*)(&Wt[c * 512 + lane * 8]),
                16, 0, 0);
    }
    {
        const int row = tid >> 1;
        const int h   = tid & 1;
        int im = in_map[base + row];
        const u32x4* src = (const u32x4*)(featbf + (size_t)(im >= 0 ? im : NVOX) * CIN + h * 32);
        u32x4 v0 = src[0], v1 = src[1], v2 = src[2], v3 = src[3];
        u32x4* dst = (u32x4*)&Fl[row * FS + h * 32];
        dst[0] = v0; dst[1] = v1; dst[2] = v2; dst[3] = v3;
    }
    __syncthreads();

    const int r = lane & 15;
    const int g = lane >> 4;

    bf16x8 af[2][2];
    bf16x8 bfr[4][2];
#pragma unroll
    for (int m = 0; m < 2; ++m)
#pragma unroll
        for (int s = 0; s < 2; ++s)
            af[m][s] = *(const bf16x8*)&Fl[(wave * 32 + m * 16 + r) * FS + s * 32 + g * 8];
#pragma unroll
    for (int n = 0; n < 4; ++n)
#pragma unroll
        for (int s = 0; s < 2; ++s)
            bfr[n][s] = *(const bf16x8*)&Wt[(n * 16 + r) * FS + s * 32 + g * 8];

    f32x4 acc[2][4];
#pragma unroll
    for (int m = 0; m < 2; ++m)
#pragma unroll
        for (int n = 0; n < 4; ++n)
            acc[m][n] = (f32x4){0.f, 0.f, 0.f, 0.f};

#pragma unroll
    for (int s = 0; s < 2; ++s)
#pragma unroll
        for (int m = 0; m < 2; ++m)
#pragma unroll
            for (int n = 0; n < 4; ++n)
                acc[m][n] = __builtin_amdgcn_mfma_f32_16x16x32_bf16(
                    af[m][s], bfr[n][s], acc[m][n], 0, 0, 0);

#pragma unroll
    for (int m = 0; m < 2; ++m)
#pragma unroll
        for (int n = 0; n < 4; ++n)
#pragma unroll
            for (int j = 0; j < 4; ++j)
                Fl[(wave * 32 + m * 16 + g * 4 + j) * FS + n * 16 + r] = f2bf(acc[m][n][j]);

    {
        const int p = tid >> 1;
        const int h = tid & 1;
        int o = out_map[base + p];
        if (o >= 0) {
            int s = startv[o] + boff[o >> 8] + rank[base + p];
            const unsigned short* src = &Fl[p * FS + h * 32];
            u32x4* dst = (u32x4*)(Ybf + (size_t)s * COUT + h * 32);
            u32x4 v0 = *(const u32x4*)(src + 0);
            u32x4 v1 = *(const u32x4*)(src + 8);
            u32x4 v2 = *(const u32x4*)(src + 16);
            u32x4 v3 = *(const u32x4*)(src + 24);
            dst[0] = v0; dst[1] = v1; dst[2] = v2; dst[3] = v3;
        }
    }
}

__global__ __launch_bounds__(256) void gather_out_kernel(
    const unsigned short* __restrict__ Y,
    const int* __restrict__ startv,
    const int* __restrict__ boff,
    const float* __restrict__ bias,
    float* __restrict__ out)
{
    const int row  = blockIdx.x * 4 + (threadIdx.x >> 6);
    const int lane = threadIdx.x & 63;
    const int c4   = (lane & 15) * 4;
    const int grp  = lane >> 4;

    const int b0 = row >> 8;
    int s0 = startv[row] + boff[b0];
    int s1 = ((row + 1) & 255) ? (startv[row + 1] + boff[b0]) : boff[b0 + 1];

    float4 acc = {0.f, 0.f, 0.f, 0.f};
    for (int j = s0 + grp; j < s1; j += 4) {
        u32x2 v = *(const u32x2*)&Y[(size_t)j * COUT + c4];
        acc.x += bfbits2f(v.x & 0xffffu);
        acc.y += bfbits2f(v.x >> 16);
        acc.z += bfbits2f(v.y & 0xffffu);
        acc.w += bfbits2f(v.y >> 16);
    }
    acc.x += __shfl_xor(acc.x, 16); acc.y += __shfl_xor(acc.y, 16);
    acc.z += __shfl_xor(acc.z, 16); acc.w += __shfl_xor(acc.w, 16);
    acc.x += __shfl_xor(acc.x, 32); acc.y += __shfl_xor(acc.y, 32);
    acc.z += __shfl_xor(acc.z, 32); acc.w += __shfl_xor(acc.w, 32);

    if (grp == 0) {
        float4 b = *(const float4*)&bias[c4];
        float4 rv = {acc.x + b.x, acc.y + b.y, acc.z + b.z, acc.w + b.w};
        *(float4*)&out[(size_t)row * COUT + c4] = rv;
    }
}

// ================= tiny-ws fallback (atomic path) =================
__global__ void init_out_kernel(float* __restrict__ out, const float* __restrict__ bias) {
    int i = blockIdx.x * blockDim.x + threadIdx.x;
    float4 b = ((const float4*)bias)[i & 15];
    ((float4*)out)[i] = b;
}

__global__ __launch_bounds__(256) void conv_atomic_kernel(
    const float* __restrict__ features, const float* __restrict__ weight,
    const int* __restrict__ in_map, const int* __restrict__ out_map,
    float* __restrict__ out)
{
    __shared__ float Wl[CIN * COUT];
    __shared__ float Fl2[128 * 65];
    const int tid = threadIdx.x;
    const int k = blockIdx.x / (PPAIR / 128);
    const int pb = blockIdx.x % (PPAIR / 128);
    const int base = k * PPAIR + pb * 128;
    const float* wk = weight + k * CIN * COUT;
#pragma unroll
    for (int j = 0; j < 4; ++j) {
        int idx = (j * 256 + tid) * 4;
        *(float4*)&Wl[idx] = *(const float4*)&wk[idx];
    }
    const int lane = tid & 63;
    const int rsel = tid >> 6;
#pragma unroll 4
    for (int j = 0; j < 128; j += 4) {
        int row = j + rsel;
        int in_row = in_map[base + row];
        float v = 0.0f;
        if (in_row >= 0) v = features[in_row * CIN + lane];
        Fl2[row * 65 + lane] = v;
    }
    __syncthreads();
    const int cg = tid & 7;
    const int pg = tid >> 3;
    float acc[4][8];
#pragma unroll
    for (int a = 0; a < 4; ++a)
#pragma unroll
        for (int b = 0; b < 8; ++b) acc[a][b] = 0.0f;
    const float* wbase = &Wl[cg * 8];
    const float* fbase = &Fl2[pg * 4 * 65];
#pragma unroll 8
    for (int i = 0; i < CIN; ++i) {
        float4 w0 = *(const float4*)&wbase[i * 64];
        float4 w1 = *(const float4*)&wbase[i * 64 + 4];
        float wv[8] = {w0.x, w0.y, w0.z, w0.w, w1.x, w1.y, w1.z, w1.w};
        float fv[4];
#pragma unroll
        for (int a = 0; a < 4; ++a) fv[a] = fbase[a * 65 + i];
#pragma unroll
        for (int a = 0; a < 4; ++a)
#pragma unroll
            for (int b = 0; b < 8; ++b)
                acc[a][b] = fmaf(fv[a], wv[b], acc[a][b]);
    }
#pragma unroll
    for (int a = 0; a < 4; ++a) {
        int pair = pg * 4 + a;
        int orow = out_map[base + pair];
        if (orow >= 0) {
            float* dst = out + orow * COUT + cg * 8;
#pragma unroll
            for (int b = 0; b < 8; ++b) unsafeAtomicAdd(dst + b, acc[a][b]);
        }
    }
}

// ================= launch =================
extern "C" void kernel_launch(void* const* d_in, const int* in_sizes, int n_in,
                              void* d_out, int out_size, void* d_ws, size_t ws_size,
                              hipStream_t stream) {
    const float* features = (const float*)d_in[0];
    const float* weight   = (const float*)d_in[1];
    const float* bias     = (const float*)d_in[2];
    const int*   in_map   = (const int*)d_in[3];
    const int*   out_map  = (const int*)d_in[4];
    float*       out      = (float*)d_out;
    char* ws = (char*)d_ws;

    if (ws_size >= WS_CAP) {
        // ---- fixed-capacity bucket path (no hist/scan, no memsets) ----
        unsigned short* Ybf   = (unsigned short*)(ws + YC_OFF);
        int* cursor  = (int*)(ws + CUR2_OFF);
        int* ovf_cnt = (int*)(ws + OVFC_OFF);
        int* ovf     = (int*)(ws + OVF_OFF);
        unsigned short* wimg2 = (unsigned short*)(ws + WIMG2_OFF);
        unsigned short* fb    = (unsigned short*)(ws + FB2_OFF);

        prep2_kernel<<<NB_F2B + NB_WP, 256, 0, stream>>>(
            features, fb, weight, wimg2, cursor, ovf_cnt);
        conv6_kernel<<<KOFF * 256, 256, 0, stream>>>(
            fb, wimg2, in_map, out_map, cursor, ovf_cnt, ovf, Ybf);
        gather_cap_kernel<<<NVOX / 4, 256, 0, stream>>>(Ybf, cursor, bias, out);
        fixup_kernel<<<256, 256, 0, stream>>>(fb, wimg2, in_map, out_map, ovf_cnt, ovf, out);
        return;
    }

    if (ws_size >= WS_FULL) {
        // ---- counting-sort path (round-7) ----
        unsigned short* Ybf  = (unsigned short*)(ws + Y_OFF);
        int* rank   = (int*)(ws + RANK_OFF);
        int* counts = (int*)(ws + CNT_OFF);
        int* startv = (int*)(ws + START_OFF);
        int* bsum   = (int*)(ws + BSUM_OFF);
        int* boff   = (int*)(ws + BOFF_OFF);
        unsigned short* wimg = (unsigned short*)(ws + WIMG_OFF);
        unsigned short* fb   = (unsigned short*)(ws + FB_OFF);

        (void)hipMemsetAsync(counts, 0, (size_t)NVOX * 4, stream);
        prep_kernel<<<NB_F2B + NB_WP + NB_RNK, 256, 0, stream>>>(
            features, fb, weight, wimg, out_map, counts, rank);
        scan1_kernel<<<NVOX / 256, 256, 0, stream>>>(counts, startv, bsum);
        scan2_kernel<<<1, 512, 0, stream>>>(bsum, boff);
        conv4_kernel<<<KOFF * 256, 256, 0, stream>>>(
            fb, wimg, in_map, out_map, startv, boff, rank, Ybf);
        gather_out_kernel<<<NVOX / 4, 256, 0, stream>>>(Ybf, startv, boff, bias, out);
        return;
    }

    // ---- tiny-ws fallback ----
    int total4 = NVOX * COUT / 4;
    init_out_kernel<<<total4 / 256, 256, 0, stream>>>(out, bias);
    conv_atomic_kernel<<<KOFF * (PPAIR / 128), 256, 0, stream>>>(
        features, weight, in_map, out_map, out);
}